// Round 3
// baseline (514.078 us; speedup 1.0000x reference)
//
#include <hip/hip_runtime.h>
#include <math.h>
#include <stdint.h>
#include <stddef.h>

// ---------- types ----------
typedef short bf16x8 __attribute__((ext_vector_type(8)));   // 8 bf16 (4 VGPRs)
typedef short bf16x4 __attribute__((ext_vector_type(4)));   // 4 bf16 (2 VGPRs)
typedef float f32x4  __attribute__((ext_vector_type(4)));

// problem constants
#define BATCH   8
#define D       1024          // model dim == GEMM K == N
#define POSD    32
#define WIN     1056          // W row length (D + POSD)
#define MBARS   2048
#define MROWS   16384         // BATCH * MBARS
#define NOUT    1024

// fp32 -> bf16 round-to-nearest-even
__device__ __forceinline__ short f2bf(float f) {
    unsigned u = __builtin_bit_cast(unsigned, f);
    u += 0x7fffu + ((u >> 16) & 1u);
    return (short)(u >> 16);
}

// ---------- kernel 1: tiny prep (unchanged, verified) ----------
// blocks [0,1024): cast W[:, :1024] -> bf16 Wb [1024][1024] (linear)
// blocks [1024,1280): FFW[mb][n] = bias[n] + sum_j ff[mb][j] * W[n][1024+j]
__global__ __launch_bounds__(256) void prep2(const float* __restrict__ W,
                                             const float* __restrict__ bias,
                                             short* __restrict__ Wb,
                                             float* __restrict__ FFW) {
    const int t   = threadIdx.x;
    const int bid = blockIdx.x;
    if (bid < NOUT) {
        const float* wr = W + (size_t)bid * WIN;
        float4 v = ((const float4*)wr)[t];                    // cols 0..1023
        bf16x4 o = { f2bf(v.x), f2bf(v.y), f2bf(v.z), f2bf(v.w) };
        *(bf16x4*)(Wb + (size_t)bid * D + t * 4) = o;
    } else {
        const int mb0 = (bid - NOUT) * 8;                     // 8 bar rows per block
        __shared__ float ff[8][32];
        if (t < 32) {
            float fr = expf((float)(t & 15) * (6.907755278982137f / 15.0f)); // linspace(0,ln1000,16)
#pragma unroll
            for (int e = 0; e < 8; ++e) {
                float pos = (float)(mb0 + e) * (1.0f / (float)(MBARS - 1));
                float ang = pos * fr;
                ff[e][t] = (t < 16) ? sinf(ang) : cosf(ang);
            }
        }
        __syncthreads();
#pragma unroll
        for (int u = 0; u < 4; ++u) {
            const int n = t + u * 256;
            const float* wp = W + (size_t)n * WIN + D;        // pos-embed columns of row n
            float4 wv[8];
#pragma unroll
            for (int blk = 0; blk < 8; ++blk) wv[blk] = ((const float4*)wp)[blk];
            const float bn = bias[n];
#pragma unroll
            for (int e = 0; e < 8; ++e) {
                float s = bn;
#pragma unroll
                for (int blk = 0; blk < 8; ++blk) {
                    s += ff[e][blk * 4 + 0] * wv[blk].x + ff[e][blk * 4 + 1] * wv[blk].y
                       + ff[e][blk * 4 + 2] * wv[blk].z + ff[e][blk * 4 + 3] * wv[blk].w;
                }
                FFW[(size_t)(mb0 + e) * NOUT + n] = s;
            }
        }
    }
}

// ---------- kernel 2: fused mean + GEMM, v3.1 ----------
// Identical to v3 except the ONE-LINE FIX: the A-fragment base pointer now includes the
// per-lane row offset r*64 (v3 read row i*16 for every lane instead of i*16+r -> absmax 2.59).
// Block = 64 bars x full N=1024, grid 256 (x read EXACTLY once).  8 waves, wave tile 64x128.
// A-only LDS, double-buffered 2x8 KB; B frags per-lane direct from L2-resident Wb; x for
// iter k+1 prefetched at top of iter k, consumed before the barrier -> vmcnt(0) drain free.
__global__ __launch_bounds__(512, 2) void fused(const float* __restrict__ x,
                                                const short* __restrict__ Wb,
                                                const float* __restrict__ FFW,
                                                float* __restrict__ out) {
    __shared__ short As[2][64 * 64];   // 2 x 8 KB, XOR-swizzled row-major [m][k]

    const int tid  = threadIdx.x;
    const int wave = tid >> 6;          // 0..7
    const int lane = tid & 63;
    const int m0   = blockIdx.x * 64;   // flat bar row; 2048 % 64 == 0, no batch straddle

    // A staging: thread t -> row ra = t>>3, octet oa = t&7; slot (oa ^ (ra&7)) breaks the
    // 16-way ds_read bank conflict (reg-staged ds_write, so the LDS side is freely swizzled)
    const int ra = tid >> 3;
    const int oa = tid & 7;
    const float* xg = x + (size_t)(m0 + ra) * 4096 + oa * 8;   // bar ra: 4 beat rows x 1024 f32
    const int aw = ra * 64 + ((oa ^ (ra & 7)) << 3);

    // fragment decode (16x16x32 bf16): row r, k-octet q
    const int r  = lane & 15;
    const int q  = lane >> 4;
    const int rx = r & 7;
    const int sl0 = ((q    ) ^ rx) << 3;   // s=0: k-octets 0..3 (A swizzle)
    const int sl1 = ((4 + q) ^ rx) << 3;   // s=1: k-octets 4..7

    // B fragment base pointers: n = wave*128 + j*16 + r, k-octet q (linear Wb, no swizzle)
    const short* bj[8];
#pragma unroll
    for (int j = 0; j < 8; ++j)
        bj[j] = Wb + (size_t)(wave * 128 + j * 16 + r) * 1024 + q * 8;

    f32x4 acc[4][8] = {};

    // ---- prologue: stage A tile for iter 0 ----
    {
        float4 X[8];
#pragma unroll
        for (int bt = 0; bt < 4; ++bt) {
            X[2 * bt]     = *(const float4*)(xg + bt * 1024);
            X[2 * bt + 1] = *(const float4*)(xg + bt * 1024 + 4);
        }
        bf16x8 av = { f2bf((X[0].x + X[2].x + X[4].x + X[6].x) * 0.25f),
                      f2bf((X[0].y + X[2].y + X[4].y + X[6].y) * 0.25f),
                      f2bf((X[0].z + X[2].z + X[4].z + X[6].z) * 0.25f),
                      f2bf((X[0].w + X[2].w + X[4].w + X[6].w) * 0.25f),
                      f2bf((X[1].x + X[3].x + X[5].x + X[7].x) * 0.25f),
                      f2bf((X[1].y + X[3].y + X[5].y + X[7].y) * 0.25f),
                      f2bf((X[1].z + X[3].z + X[5].z + X[7].z) * 0.25f),
                      f2bf((X[1].w + X[3].w + X[5].w + X[7].w) * 0.25f) };
        *(bf16x8*)(&As[0][aw]) = av;
    }
    __syncthreads();

#pragma unroll 2
    for (int k = 0; k < 16; ++k) {
        const short* ap = &As[k & 1][r * 64];         // <-- FIX: per-lane row base restored
        const int kof = k * 64;                       // k offset in shorts within a Wb row

        // prefetch x for iter k+1 (consumed at the bottom of this iter)
        float4 X[8];
        if (k < 15) {
            const float* xk = xg + (k + 1) * 64;
#pragma unroll
            for (int bt = 0; bt < 4; ++bt) {
                X[2 * bt]     = *(const float4*)(xk + bt * 1024);
                X[2 * bt + 1] = *(const float4*)(xk + bt * 1024 + 4);
            }
        }

#pragma unroll
        for (int s = 0; s < 2; ++s) {
            const int sl = s ? sl1 : sl0;
            bf16x8 a[4], b[8];
#pragma unroll
            for (int i = 0; i < 4; ++i) a[i] = *(const bf16x8*)(ap + i * 1024 + sl);
#pragma unroll
            for (int j = 0; j < 8; ++j) b[j] = *(const bf16x8*)(bj[j] + kof + s * 32);
#pragma unroll
            for (int i = 0; i < 4; ++i)
#pragma unroll
                for (int j = 0; j < 8; ++j)
                    acc[i][j] = __builtin_amdgcn_mfma_f32_16x16x32_bf16(a[i], b[j], acc[i][j], 0, 0, 0);
        }

        if (k < 15) {
            bf16x8 av = { f2bf((X[0].x + X[2].x + X[4].x + X[6].x) * 0.25f),
                          f2bf((X[0].y + X[2].y + X[4].y + X[6].y) * 0.25f),
                          f2bf((X[0].z + X[2].z + X[4].z + X[6].z) * 0.25f),
                          f2bf((X[0].w + X[2].w + X[4].w + X[6].w) * 0.25f),
                          f2bf((X[1].x + X[3].x + X[5].x + X[7].x) * 0.25f),
                          f2bf((X[1].y + X[3].y + X[5].y + X[7].y) * 0.25f),
                          f2bf((X[1].z + X[3].z + X[5].z + X[7].z) * 0.25f),
                          f2bf((X[1].w + X[3].w + X[5].w + X[7].w) * 0.25f) };
            *(bf16x8*)(&As[(k + 1) & 1][aw]) = av;
        }
        __syncthreads();
    }

    // epilogue: C/D layout col = lane&15, row = (lane>>4)*4 + reg; FFW (bias folded) added
    const int mbb = m0 & (MBARS - 1);
    const int c0  = wave * 128 + r;
    const int rt0 = q << 2;
#pragma unroll
    for (int i = 0; i < 4; ++i)
#pragma unroll
        for (int rg = 0; rg < 4; ++rg) {
            const int rt = i * 16 + rt0 + rg;
            const float* fw = FFW + (size_t)(mbb + rt) * NOUT + c0;
            float* cp = out + (size_t)(m0 + rt) * NOUT + c0;
#pragma unroll
            for (int j = 0; j < 8; ++j)
                cp[j * 16] = acc[i][j][rg] + fw[j * 16];
        }
}

extern "C" void kernel_launch(void* const* d_in, const int* in_sizes, int n_in,
                              void* d_out, int out_size, void* d_ws, size_t ws_size,
                              hipStream_t stream) {
    const float* x    = (const float*)d_in[0];   // [8, 8192, 1024]
    const float* W    = (const float*)d_in[1];   // [1024, 1056]
    const float* bias = (const float*)d_in[2];   // [1024]
    float* out = (float*)d_out;                  // [8, 2048, 1024]

    // workspace: Wb bf16 [1024][1024] (2 MB) then FFW f32 [2048][1024] (8 MB)
    short* Wb  = (short*)d_ws;
    float* FFW = (float*)((char*)d_ws + (size_t)NOUT * D * sizeof(short));

    prep2<<<dim3(NOUT + MBARS / 8), dim3(256), 0, stream>>>(W, bias, Wb, FFW);
    fused<<<dim3(MROWS / 64), dim3(512), 0, stream>>>(x, Wb, FFW, out);
}

// Round 4
// 434.541 us; speedup vs baseline: 1.1830x; 1.1830x over previous
//
#include <hip/hip_runtime.h>
#include <math.h>
#include <stdint.h>
#include <stddef.h>

// ---------- types ----------
typedef short bf16x8 __attribute__((ext_vector_type(8)));   // 8 bf16 (4 VGPRs)
typedef short bf16x4 __attribute__((ext_vector_type(4)));   // 4 bf16 (2 VGPRs)
typedef float f32x4  __attribute__((ext_vector_type(4)));

// problem constants
#define BATCH   8
#define D       1024          // model dim == GEMM K == N (clean 1024 after FFW fold)
#define POSD    32
#define WIN     1056          // W row length (D + POSD)
#define MBARS   2048
#define MROWS   16384         // BATCH * MBARS
#define NOUT    1024

// fp32 -> bf16 round-to-nearest-even
__device__ __forceinline__ short f2bf(float f) {
    unsigned u = __builtin_bit_cast(unsigned, f);
    u += 0x7fffu + ((u >> 16) & 1u);
    return (short)(u >> 16);
}

// async global -> LDS, 16B/lane; LDS dest = wave-uniform base + lane*16
__device__ __forceinline__ void async_load16(const short* g, short* l) {
    __builtin_amdgcn_global_load_lds((__attribute__((address_space(1))) void*)g,
                                     (__attribute__((address_space(3))) void*)l,
                                     16, 0, 0);
}

// ---------- kernel 1: prep ----------
// blocks [0, MROWS):           segment mean (K=4) -> h bf16 [MROWS][1024]   (linear, no pad)
// blocks [MROWS, MROWS+1024):  cast W[:, :1024] -> Wb bf16 [1024][1024]
// blocks [MROWS+1024, +256):   FFW[mb][n] = bias[n] + sum_j ff[mb][j]*W[n][1024+j]  (8 mb/block)
// FFW folds fourier cols + bias into a per-(mb,n) f32 table -> GEMM gets a clean K=1024.
__global__ __launch_bounds__(256) void prep3(const float* __restrict__ x,
                                             const float* __restrict__ W,
                                             const float* __restrict__ bias,
                                             short* __restrict__ h,
                                             short* __restrict__ Wb,
                                             float* __restrict__ FFW) {
    const int t   = threadIdx.x;
    const int bid = blockIdx.x;
    if (bid < MROWS) {
        // 4 beat rows are 16 KB contiguous at x + bid*4096
        const float4* src = (const float4*)(x + (size_t)bid * 4096);
        float4 s0 = src[t], s1 = src[t + 256], s2 = src[t + 512], s3 = src[t + 768];
        bf16x4 o = { f2bf((s0.x + s1.x + s2.x + s3.x) * 0.25f),
                     f2bf((s0.y + s1.y + s2.y + s3.y) * 0.25f),
                     f2bf((s0.z + s1.z + s2.z + s3.z) * 0.25f),
                     f2bf((s0.w + s1.w + s2.w + s3.w) * 0.25f) };
        *(bf16x4*)(h + (size_t)bid * D + t * 4) = o;
    } else if (bid < MROWS + NOUT) {
        const int rw = bid - MROWS;
        float4 v = ((const float4*)(W + (size_t)rw * WIN))[t];   // cols 0..1023
        bf16x4 o = { f2bf(v.x), f2bf(v.y), f2bf(v.z), f2bf(v.w) };
        *(bf16x4*)(Wb + (size_t)rw * D + t * 4) = o;
    } else {
        const int mb0 = (bid - MROWS - NOUT) * 8;                // 8 bar rows per block
        __shared__ float ff[8][32];
        if (t < 32) {
            float fr = expf((float)(t & 15) * (6.907755278982137f / 15.0f)); // linspace(0,ln1000,16)
#pragma unroll
            for (int e = 0; e < 8; ++e) {
                float pos = (float)(mb0 + e) * (1.0f / (float)(MBARS - 1));
                float ang = pos * fr;
                ff[e][t] = (t < 16) ? sinf(ang) : cosf(ang);
            }
        }
        __syncthreads();
#pragma unroll
        for (int u = 0; u < 4; ++u) {
            const int n = t + u * 256;
            const float* wp = W + (size_t)n * WIN + D;           // pos-embed columns of row n
            float4 wv[8];
#pragma unroll
            for (int blk = 0; blk < 8; ++blk) wv[blk] = ((const float4*)wp)[blk];
            const float bn = bias[n];
#pragma unroll
            for (int e = 0; e < 8; ++e) {
                float s = bn;
#pragma unroll
                for (int blk = 0; blk < 8; ++blk) {
                    s += ff[e][blk * 4 + 0] * wv[blk].x + ff[e][blk * 4 + 1] * wv[blk].y
                       + ff[e][blk * 4 + 2] * wv[blk].z + ff[e][blk * 4 + 3] * wv[blk].w;
                }
                FFW[(size_t)(mb0 + e) * NOUT + n] = s;
            }
        }
    }
}

// ---------- kernel 2: C[16384,1024] = h @ Wb^T + FFW ----------
// The round-0 HARNESS-PROVEN structure (128x128 tile, BK=64, 256 threads, 2x2 waves x 4x4 MFMA,
// global_load_lds staging with XOR swizzle applied on the pre-swizzled GLOBAL source octet),
// upgraded: K = 1024 clean (16 iters, was 17 ragged) and FFW epilogue replaces bias.
// 1024 blocks -> 3-4 per CU: cross-block overlap hides the per-step barrier drain (the thing
// the 1-block/CU fused variants of rounds 1-3 fatally lacked).  acc = 64 AGPR, no spill.
__global__ __launch_bounds__(256) void gemm_bt(const short* __restrict__ A,   // h  [MROWS, D]
                                               const short* __restrict__ B,   // Wb [NOUT, D]
                                               const float* __restrict__ FFW, // [MBARS, NOUT]
                                               float* __restrict__ C) {
    __shared__ short As[128 * 64];   // 16 KB, swizzled row-major [m][k]
    __shared__ short Bs[128 * 64];   // 16 KB

    const int tid  = threadIdx.x;
    const int wave = tid >> 6;
    const int lane = tid & 63;
    const int wrow = wave >> 1;          // 2x2 wave grid -> 64x64 per wave
    const int wcol = wave & 1;

    const int m0 = blockIdx.x * 128;     // gridDim.x = 128
    const int n0 = blockIdx.y * 128;     // gridDim.y = 8

    // staging: issue covers 32 rows x 64 cols; thread t -> row t>>3, octet (t&7)^swizzle
    const int r8   = tid >> 3;                    // 0..31
    const int soct = (tid & 7) ^ (r8 & 7);        // swizzled global octet
    const short* ag = A + (size_t)(m0 + r8) * D + soct * 8;
    const short* bg = B + (size_t)(n0 + r8) * D + soct * 8;
    short* al = As + wave * 512;                  // wave-uniform; HW adds lane*16B
    short* bl = Bs + wave * 512;

    // fragment decode
    const int r  = lane & 15;
    const int q  = lane >> 4;                     // k-octet within 32-wide step
    const int rx = r & 7;
    const short* afr = As + (wrow * 64 + r) * 64;
    const short* bfr = Bs + (wcol * 64 + r) * 64;
    const int sl0 = ((q    ) ^ rx) * 8;           // s=0: k-octets 0..3
    const int sl1 = ((4 + q) ^ rx) * 8;           // s=1: k-octets 4..7

    f32x4 acc[4][4] = {};

    for (int k0 = 0; k0 < D; k0 += 64) {          // 16 iterations
        __syncthreads();
#pragma unroll
        for (int i = 0; i < 4; ++i) {             // 4 issues x 32 rows each, A and B
            async_load16(ag + k0 + (size_t)i * 32 * D, al + i * 2048);
            async_load16(bg + k0 + (size_t)i * 32 * D, bl + i * 2048);
        }
        __syncthreads();

#pragma unroll
        for (int s = 0; s < 2; ++s) {
            const int sl = s ? sl1 : sl0;
            bf16x8 a[4], b[4];
#pragma unroll
            for (int i = 0; i < 4; ++i) {
                a[i] = *(const bf16x8*)(afr + i * 1024 + sl);
                b[i] = *(const bf16x8*)(bfr + i * 1024 + sl);
            }
#pragma unroll
            for (int i = 0; i < 4; ++i)
#pragma unroll
                for (int j = 0; j < 4; ++j)
                    acc[i][j] = __builtin_amdgcn_mfma_f32_16x16x32_bf16(a[i], b[j], acc[i][j], 0, 0, 0);
        }
    }

    // epilogue: C/D layout col = lane&15, row = (lane>>4)*4 + reg; add FFW[row%2048][col]
    // (bias folded into FFW; m0 is a multiple of 128 so row%2048 == row & 2047 stays in-batch)
    const int rr0 = m0 + wrow * 64 + (q << 2);
    const int c0  = n0 + wcol * 64 + r;
#pragma unroll
    for (int i = 0; i < 4; ++i)
#pragma unroll
        for (int rg = 0; rg < 4; ++rg) {
            const int row = rr0 + i * 16 + rg;
            const float* fw = FFW + (size_t)(row & (MBARS - 1)) * NOUT + c0;
            float* cp = C + (size_t)row * NOUT + c0;
#pragma unroll
            for (int j = 0; j < 4; ++j)
                cp[j * 16] = acc[i][j][rg] + fw[j * 16];
        }
}

extern "C" void kernel_launch(void* const* d_in, const int* in_sizes, int n_in,
                              void* d_out, int out_size, void* d_ws, size_t ws_size,
                              hipStream_t stream) {
    const float* x    = (const float*)d_in[0];   // [8, 8192, 1024]
    const float* W    = (const float*)d_in[1];   // [1024, 1056]
    const float* bias = (const float*)d_in[2];   // [1024]
    float* out = (float*)d_out;                  // [8, 2048, 1024]

    // workspace: Wb bf16 [1024][1024] (2 MB) | FFW f32 [2048][1024] (8 MB) | h bf16 [16384][1024] (32 MB)
    short* Wb  = (short*)d_ws;
    float* FFW = (float*)((char*)d_ws + (size_t)NOUT * D * sizeof(short));
    short* h   = (short*)((char*)FFW + (size_t)MBARS * NOUT * sizeof(float));

    prep3  <<<dim3(MROWS + NOUT + MBARS / 8), dim3(256), 0, stream>>>(x, W, bias, h, Wb, FFW);
    gemm_bt<<<dim3(MROWS / 128, NOUT / 128), dim3(256), 0, stream>>>(h, Wb, FFW, out);
}